// Round 4
// baseline (49.933 us; speedup 1.0000x reference)
//
#include <hip/hip_runtime.h>

constexpr int GRID_SZ = 5;
constexpr int N_CTRL  = 25;
constexpr int IMG_H   = 256;
constexpr int IMG_W   = 192;
constexpr int BATCH   = 64;
constexpr int BCHUNK  = 8;    // batches per block (looped, pipelined)
constexpr int PLANE   = IMG_H * IMG_W;
constexpr int PIX_BLOCKS = PLANE / 256;             // 192
constexpr int NWG = PIX_BLOCKS * (BATCH / BCHUNK);  // 1536, divisible by 8
constexpr float RBF_SCALE = 10.0f;
constexpr float OFF_SCALE = 0.3f;

__global__ __launch_bounds__(256) void tps_warp_kernel(
    const float* __restrict__ cloth,   // (64,3,256,192)
    const float* __restrict__ theta,   // (64,50)
    float* __restrict__ out)           // (64,3,256,192)
{
    // XCD swizzle: flat&7 = XCD id -> each XCD owns ONE whole batch-chunk
    // (8 images ~ its private 4 MiB L2). Kept: FETCH dropped 117->17 MB.
    const int flat = blockIdx.x;
    const int bc   = flat & 7;
    const int pb   = flat >> 3;
    const int b0   = bc * BCHUNK;

    const int pix = pb * 256 + threadIdx.x;
    const int hh = pix / IMG_W;
    const int ww = pix - hh * IMG_W;
    const float mx = -1.0f + (2.0f / (IMG_W - 1)) * (float)ww;
    const float my = -1.0f + (2.0f / (IMG_H - 1)) * (float)hh;

    // separable RBF basis: 10 exps + 25 muls (once for all 8 batches).
    // Fold OFF_SCALE into wgt so raw theta (in SGPRs) feeds the FMAs.
    float ex[GRID_SZ], ey[GRID_SZ];
#pragma unroll
    for (int k = 0; k < GRID_SZ; ++k) {
        const float c = -0.9f + 0.45f * (float)k;
        const float dx = mx - c;
        const float dy = my - c;
        ex[k] = __expf(-dx * dx * RBF_SCALE);
        ey[k] = __expf(-dy * dy * RBF_SCALE);
    }
    float wgt[N_CTRL];
#pragma unroll
    for (int n = 0; n < N_CTRL; ++n)
        wgt[n] = OFF_SCALE * ex[n % GRID_SZ] * ey[n / GRID_SZ];

    // ---- phase A: sample coords per batch.
    // theta indices are block-uniform -> compiler emits s_load into SGPRs;
    // v_fmac_f32 consumes the SGPR operand directly. NO LDS anywhere.
    float sxp[BCHUNK], syp[BCHUNK];
#pragma unroll
    for (int bi = 0; bi < BCHUNK; ++bi) {
        const float* __restrict__ th = theta + (size_t)(b0 + bi) * (2 * N_CTRL);
        float ox = 0.0f, oy = 0.0f;
#pragma unroll
        for (int n = 0; n < N_CTRL; ++n) {
            ox = fmaf(th[2 * n + 0], wgt[n], ox);
            oy = fmaf(th[2 * n + 1], wgt[n], oy);
        }
        const float gx = fminf(fmaxf(mx + ox, -1.0f), 1.0f);
        const float gy = fminf(fmaxf(my + oy, -1.0f), 1.0f);
        sxp[bi] = (gx + 1.0f) * (0.5f * (float)(IMG_W - 1));  // in [0, W-1]
        syp[bi] = (gy + 1.0f) * (0.5f * (float)(IMG_H - 1));  // in [0, H-1]
    }

    const size_t img_stride = (size_t)3 * PLANE;
    const float* imgb = cloth + (size_t)b0 * img_stride;
    float*       outb = out   + (size_t)b0 * img_stride + pix;

    // ---- phase B: 1-deep pipelined gather/blend over 8 batches
    float v[2][12];

    auto issue = [&](int bi, int slot) {
        const float x = sxp[bi];
        const float y = syp[bi];
        const int x0 = (int)x;               // x >= 0, so trunc == floor
        const int y0 = (int)y;
        const int x1 = min(x0 + 1, IMG_W - 1);
        const int y1 = min(y0 + 1, IMG_H - 1);
        const int a = y0 * IMG_W + x0;
        const int b = y0 * IMG_W + x1;
        const int c = y1 * IMG_W + x0;
        const int d = y1 * IMG_W + x1;
        const float* img = imgb + (size_t)bi * img_stride;
#pragma unroll
        for (int ch = 0; ch < 3; ++ch) {
            const float* pc = img + ch * PLANE;
            v[slot][ch * 4 + 0] = pc[a];
            v[slot][ch * 4 + 1] = pc[b];
            v[slot][ch * 4 + 2] = pc[c];
            v[slot][ch * 4 + 3] = pc[d];
        }
    };

    auto blend = [&](int bi, int slot) {
        const float x = sxp[bi];
        const float y = syp[bi];
        const float wx = x - floorf(x);
        const float wy = y - floorf(y);
        const float wa = (1.0f - wx) * (1.0f - wy);
        const float wb = wx * (1.0f - wy);
        const float wc = (1.0f - wx) * wy;
        const float wd = wx * wy;
        float* op = outb + (size_t)bi * img_stride;
#pragma unroll
        for (int ch = 0; ch < 3; ++ch) {
            const float r = wa * v[slot][ch * 4 + 0] + wb * v[slot][ch * 4 + 1] +
                            wc * v[slot][ch * 4 + 2] + wd * v[slot][ch * 4 + 3];
            __builtin_nontemporal_store(r, op + ch * PLANE);  // output never re-read
        }
    };

    issue(0, 0);
#pragma unroll
    for (int bi = 0; bi < BCHUNK; ++bi) {
        if (bi + 1 < BCHUNK) issue(bi + 1, (bi + 1) & 1);
        blend(bi, bi & 1);
    }
}

extern "C" void kernel_launch(void* const* d_in, const int* in_sizes, int n_in,
                              void* d_out, int out_size, void* d_ws, size_t ws_size,
                              hipStream_t stream) {
    const float* cloth = (const float*)d_in[0];
    const float* theta = (const float*)d_in[1];
    float* out = (float*)d_out;

    tps_warp_kernel<<<dim3(NWG), dim3(256), 0, stream>>>(cloth, theta, out);
}

// Round 5
// 40.806 us; speedup vs baseline: 1.2237x; 1.2237x over previous
//
#include <hip/hip_runtime.h>

constexpr int GRID_SZ = 5;
constexpr int N_CTRL  = 25;
constexpr int IMG_H   = 256;
constexpr int IMG_W   = 192;
constexpr int BATCH   = 64;
constexpr int BCHUNK  = 8;    // batches per block (looped, pipelined)
constexpr int PLANE   = IMG_H * IMG_W;
constexpr int PIX_BLOCKS = PLANE / 256;             // 192
constexpr int NWG = PIX_BLOCKS * (BATCH / BCHUNK);  // 1536, divisible by 8
constexpr float RBF_SCALE = 10.0f;
constexpr float OFF_SCALE = 0.3f;

__global__ __launch_bounds__(256) void tps_warp_kernel(
    const float* __restrict__ cloth,   // (64,3,256,192)
    const float* __restrict__ theta,   // (64,50)
    float* __restrict__ out)           // (64,3,256,192)
{
    // XCD swizzle: flat&7 = XCD id -> each XCD owns ONE whole batch-chunk
    // (8 images ~ its private 4 MiB L2). Kept: FETCH dropped 117->17 MB.
    const int flat = blockIdx.x;
    const int bc   = flat & 7;
    const int pb   = flat >> 3;
    const int b0   = bc * BCHUNK;

    const int pix = pb * 256 + threadIdx.x;
    const int hh = pix / IMG_W;
    const int ww = pix - hh * IMG_W;
    const float mx = -1.0f + (2.0f / (IMG_W - 1)) * (float)ww;
    const float my = -1.0f + (2.0f / (IMG_H - 1)) * (float)hh;

    // separable RBF basis: 10 exps + 25 muls (once for all 8 batches).
    // OFF_SCALE folded into wgt so raw theta (SGPR-resident) feeds the FMAs.
    float ex[GRID_SZ], ey[GRID_SZ];
#pragma unroll
    for (int k = 0; k < GRID_SZ; ++k) {
        const float c = -0.9f + 0.45f * (float)k;
        const float dx = mx - c;
        const float dy = my - c;
        ex[k] = __expf(-dx * dx * RBF_SCALE);
        ey[k] = __expf(-dy * dy * RBF_SCALE);
    }
    float wgt[N_CTRL];
#pragma unroll
    for (int n = 0; n < N_CTRL; ++n)
        wgt[n] = OFF_SCALE * ex[n % GRID_SZ] * ey[n / GRID_SZ];

    // ---- phase A: sample coords per batch (theta via SGPR s_loads, no LDS)
    float sxp[BCHUNK], syp[BCHUNK];
#pragma unroll
    for (int bi = 0; bi < BCHUNK; ++bi) {
        const float* __restrict__ th = theta + (size_t)(b0 + bi) * (2 * N_CTRL);
        float ox = 0.0f, oy = 0.0f;
#pragma unroll
        for (int n = 0; n < N_CTRL; ++n) {
            ox = fmaf(th[2 * n + 0], wgt[n], ox);
            oy = fmaf(th[2 * n + 1], wgt[n], oy);
        }
        const float gx = fminf(fmaxf(mx + ox, -1.0f), 1.0f);
        const float gy = fminf(fmaxf(my + oy, -1.0f), 1.0f);
        sxp[bi] = (gx + 1.0f) * (0.5f * (float)(IMG_W - 1));  // in [0, W-1]
        syp[bi] = (gy + 1.0f) * (0.5f * (float)(IMG_H - 1));  // in [0, H-1]
    }

    const size_t img_stride = (size_t)3 * PLANE;
    const float* imgb = cloth + (size_t)b0 * img_stride;
    float*       outb = out   + (size_t)b0 * img_stride + pix;

    // ---- phase B: 1-deep pipelined 2x2-patch gather (float2 rows) + blend
    // x0 = min(floor(x), W-2), wx = x - x0 is EXACTLY the reference border
    // clamp for x in [0, W-1]: interior unchanged; x == W-1 gives wx = 1.
    float2 v[2][6];   // [slot][ch*2 + row]

    auto issue = [&](int bi, int slot) {
        const int x0 = min((int)sxp[bi], IMG_W - 2);
        const int y0 = min((int)syp[bi], IMG_H - 2);
        const int base = y0 * IMG_W + x0;
        const float* img = imgb + (size_t)bi * img_stride;
#pragma unroll
        for (int ch = 0; ch < 3; ++ch) {
            const float* pc = img + ch * PLANE + base;
            v[slot][ch * 2 + 0] = *reinterpret_cast<const float2*>(pc);
            v[slot][ch * 2 + 1] = *reinterpret_cast<const float2*>(pc + IMG_W);
        }
    };

    auto blend = [&](int bi, int slot) {
        const float x = sxp[bi];
        const float y = syp[bi];
        const float wx = x - (float)min((int)x, IMG_W - 2);
        const float wy = y - (float)min((int)y, IMG_H - 2);
        float* op = outb + (size_t)bi * img_stride;
#pragma unroll
        for (int ch = 0; ch < 3; ++ch) {
            const float2 r0 = v[slot][ch * 2 + 0];
            const float2 r1 = v[slot][ch * 2 + 1];
            const float top = fmaf(wx, r0.y - r0.x, r0.x);
            const float bot = fmaf(wx, r1.y - r1.x, r1.x);
            const float r   = fmaf(wy, bot - top, top);
            __builtin_nontemporal_store(r, op + ch * PLANE);  // output never re-read
        }
    };

    issue(0, 0);
#pragma unroll
    for (int bi = 0; bi < BCHUNK; ++bi) {
        if (bi + 1 < BCHUNK) issue(bi + 1, (bi + 1) & 1);
        blend(bi, bi & 1);
    }
}

extern "C" void kernel_launch(void* const* d_in, const int* in_sizes, int n_in,
                              void* d_out, int out_size, void* d_ws, size_t ws_size,
                              hipStream_t stream) {
    const float* cloth = (const float*)d_in[0];
    const float* theta = (const float*)d_in[1];
    float* out = (float*)d_out;

    tps_warp_kernel<<<dim3(NWG), dim3(256), 0, stream>>>(cloth, theta, out);
}

// Round 6
// 38.783 us; speedup vs baseline: 1.2875x; 1.0522x over previous
//
#include <hip/hip_runtime.h>

constexpr int GRID_SZ = 5;
constexpr int N_CTRL  = 25;
constexpr int IMG_H   = 256;
constexpr int IMG_W   = 192;
constexpr int BATCH   = 64;
constexpr int BCHUNK  = 4;    // batches per block (looped, pipelined)
constexpr int PLANE   = IMG_H * IMG_W;
constexpr int PIX_BLOCKS = PLANE / 256;             // 192
constexpr int NWG = PIX_BLOCKS * (BATCH / BCHUNK);  // 3072, divisible by 8
constexpr float RBF_SCALE = 10.0f;
constexpr float OFF_SCALE = 0.3f;

__global__ __launch_bounds__(256) void tps_warp_kernel(
    const float* __restrict__ cloth,   // (64,3,256,192)
    const float* __restrict__ theta,   // (64,50)
    float* __restrict__ out)           // (64,3,256,192)
{
    // XCD-contiguous swizzle: XCD k owns wg range [k*NWG/8, (k+1)*NWG/8)
    // = 2 batch-chunks = 8 images ~ its private 4 MiB L2.
    const int flat = blockIdx.x;
    const int wg   = (flat & 7) * (NWG / 8) + (flat >> 3);
    const int pb   = wg % PIX_BLOCKS;
    const int bc   = wg / PIX_BLOCKS;
    const int b0   = bc * BCHUNK;

    const int pix = pb * 256 + threadIdx.x;
    const int hh = pix / IMG_W;
    const int ww = pix - hh * IMG_W;
    const float mx = -1.0f + (2.0f / (IMG_W - 1)) * (float)ww;
    const float my = -1.0f + (2.0f / (IMG_H - 1)) * (float)hh;

    // separable RBF basis: 10 exps + 25 muls; OFF_SCALE folded in.
    float ex[GRID_SZ], ey[GRID_SZ];
#pragma unroll
    for (int k = 0; k < GRID_SZ; ++k) {
        const float c = -0.9f + 0.45f * (float)k;
        const float dx = mx - c;
        const float dy = my - c;
        ex[k] = __expf(-dx * dx * RBF_SCALE);
        ey[k] = __expf(-dy * dy * RBF_SCALE);
    }
    float wgt[N_CTRL];
#pragma unroll
    for (int n = 0; n < N_CTRL; ++n)
        wgt[n] = OFF_SCALE * ex[n % GRID_SZ] * ey[n / GRID_SZ];

    // ---- phase A: sample coords per batch (theta via SGPR s_loads, no LDS)
    float sxp[BCHUNK], syp[BCHUNK];
#pragma unroll
    for (int bi = 0; bi < BCHUNK; ++bi) {
        const float* __restrict__ th = theta + (size_t)(b0 + bi) * (2 * N_CTRL);
        float ox = 0.0f, oy = 0.0f;
#pragma unroll
        for (int n = 0; n < N_CTRL; ++n) {
            ox = fmaf(th[2 * n + 0], wgt[n], ox);
            oy = fmaf(th[2 * n + 1], wgt[n], oy);
        }
        const float gx = fminf(fmaxf(mx + ox, -1.0f), 1.0f);
        const float gy = fminf(fmaxf(my + oy, -1.0f), 1.0f);
        sxp[bi] = (gx + 1.0f) * (0.5f * (float)(IMG_W - 1));  // in [0, W-1]
        syp[bi] = (gy + 1.0f) * (0.5f * (float)(IMG_H - 1));  // in [0, H-1]
    }

    const size_t img_stride = (size_t)3 * PLANE;
    const float* imgb = cloth + (size_t)b0 * img_stride;
    float*       outb = out   + (size_t)b0 * img_stride + pix;

    // ---- phase B: pipelined gather -> blend into REGISTERS.
    // NO stores inside the loop: in-order vmcnt would couple each load-wait
    // to the previous step's store retirement (~HBM latency for NT stores).
    float2 v[2][6];          // [slot][ch*2 + row], in-flight patches
    float  res[BCHUNK][3];   // blended results, stored at the very end

    auto issue = [&](int bi, int slot) {
        const int x0 = min((int)sxp[bi], IMG_W - 2);
        const int y0 = min((int)syp[bi], IMG_H - 2);
        const int base = y0 * IMG_W + x0;
        const float* img = imgb + (size_t)bi * img_stride;
#pragma unroll
        for (int ch = 0; ch < 3; ++ch) {
            const float* pc = img + ch * PLANE + base;
            v[slot][ch * 2 + 0] = *reinterpret_cast<const float2*>(pc);
            v[slot][ch * 2 + 1] = *reinterpret_cast<const float2*>(pc + IMG_W);
        }
    };

    auto blend = [&](int bi, int slot) {
        const float x = sxp[bi];
        const float y = syp[bi];
        const float wx = x - (float)min((int)x, IMG_W - 2);
        const float wy = y - (float)min((int)y, IMG_H - 2);
#pragma unroll
        for (int ch = 0; ch < 3; ++ch) {
            const float2 r0 = v[slot][ch * 2 + 0];
            const float2 r1 = v[slot][ch * 2 + 1];
            const float top = fmaf(wx, r0.y - r0.x, r0.x);
            const float bot = fmaf(wx, r1.y - r1.x, r1.x);
            res[bi][ch]     = fmaf(wy, bot - top, top);
        }
    };

    issue(0, 0);
#pragma unroll
    for (int bi = 0; bi < BCHUNK; ++bi) {
        if (bi + 1 < BCHUNK) issue(bi + 1, (bi + 1) & 1);
        blend(bi, bi & 1);
    }

    // ---- phase C: all stores at the end (nothing waits on them afterwards;
    // NT keeps 37 MB of write data from evicting the L2-resident input).
#pragma unroll
    for (int bi = 0; bi < BCHUNK; ++bi) {
        float* op = outb + (size_t)bi * img_stride;
#pragma unroll
        for (int ch = 0; ch < 3; ++ch)
            __builtin_nontemporal_store(res[bi][ch], op + ch * PLANE);
    }
}

extern "C" void kernel_launch(void* const* d_in, const int* in_sizes, int n_in,
                              void* d_out, int out_size, void* d_ws, size_t ws_size,
                              hipStream_t stream) {
    const float* cloth = (const float*)d_in[0];
    const float* theta = (const float*)d_in[1];
    float* out = (float*)d_out;

    tps_warp_kernel<<<dim3(NWG), dim3(256), 0, stream>>>(cloth, theta, out);
}

// Round 7
// 37.526 us; speedup vs baseline: 1.3306x; 1.0335x over previous
//
#include <hip/hip_runtime.h>

constexpr int GRID_SZ = 5;
constexpr int N_CTRL  = 25;
constexpr int IMG_H   = 256;
constexpr int IMG_W   = 192;
constexpr int BATCH   = 64;
constexpr int BCHUNK  = 4;    // batches per block; ALL prefetched (depth-4 MLP)
constexpr int PLANE   = IMG_H * IMG_W;
constexpr int PIX_BLOCKS = PLANE / 256;             // 192
constexpr int NWG = PIX_BLOCKS * (BATCH / BCHUNK);  // 3072, divisible by 8
constexpr float RBF_SCALE = 10.0f;
constexpr float OFF_SCALE = 0.3f;

__global__ __launch_bounds__(256) void tps_warp_kernel(
    const float* __restrict__ cloth,   // (64,3,256,192)
    const float* __restrict__ theta,   // (64,50)
    float* __restrict__ out)           // (64,3,256,192)
{
    // XCD-contiguous swizzle (keeps HBM FETCH at compulsory ~17 MB).
    const int flat = blockIdx.x;
    const int wg   = (flat & 7) * (NWG / 8) + (flat >> 3);
    const int pb   = wg % PIX_BLOCKS;
    const int bc   = wg / PIX_BLOCKS;
    const int b0   = bc * BCHUNK;

    const int pix = pb * 256 + threadIdx.x;
    const int hh = pix / IMG_W;
    const int ww = pix - hh * IMG_W;
    const float mx = -1.0f + (2.0f / (IMG_W - 1)) * (float)ww;
    const float my = -1.0f + (2.0f / (IMG_H - 1)) * (float)hh;

    // separable RBF basis: 10 exps + 25 muls; OFF_SCALE folded in.
    float ex[GRID_SZ], ey[GRID_SZ];
#pragma unroll
    for (int k = 0; k < GRID_SZ; ++k) {
        const float c = -0.9f + 0.45f * (float)k;
        const float dx = mx - c;
        const float dy = my - c;
        ex[k] = __expf(-dx * dx * RBF_SCALE);
        ey[k] = __expf(-dy * dy * RBF_SCALE);
    }
    float wgt[N_CTRL];
#pragma unroll
    for (int n = 0; n < N_CTRL; ++n)
        wgt[n] = OFF_SCALE * ex[n % GRID_SZ] * ey[n / GRID_SZ];

    // ---- phase A: sample coords per batch (theta via SGPR s_loads, no LDS)
    float sxp[BCHUNK], syp[BCHUNK];
#pragma unroll
    for (int bi = 0; bi < BCHUNK; ++bi) {
        const float* __restrict__ th = theta + (size_t)(b0 + bi) * (2 * N_CTRL);
        float ox = 0.0f, oy = 0.0f;
#pragma unroll
        for (int n = 0; n < N_CTRL; ++n) {
            ox = fmaf(th[2 * n + 0], wgt[n], ox);
            oy = fmaf(th[2 * n + 1], wgt[n], oy);
        }
        const float gx = fminf(fmaxf(mx + ox, -1.0f), 1.0f);
        const float gy = fminf(fmaxf(my + oy, -1.0f), 1.0f);
        sxp[bi] = (gx + 1.0f) * (0.5f * (float)(IMG_W - 1));  // in [0, W-1]
        syp[bi] = (gy + 1.0f) * (0.5f * (float)(IMG_H - 1));  // in [0, H-1]
    }

    const size_t img_stride = (size_t)3 * PLANE;
    const float* imgb = cloth + (size_t)b0 * img_stride;
    float*       outb = out   + (size_t)b0 * img_stride + pix;

    // ---- phase B: issue ALL 24 gather loads (depth-4 MLP, one latency
    // exposure per wave). Gathers miss the 4 MiB XCD-L2 (per-XCD footprint
    // is 4.7 MB by construction) and return from Infinity Cache; deep MLP
    // is the only lever against that latency.
    float2 v[BCHUNK][6];     // [batch][ch*2 + row] — all statically indexed
#pragma unroll
    for (int bi = 0; bi < BCHUNK; ++bi) {
        const int x0 = min((int)sxp[bi], IMG_W - 2);
        const int y0 = min((int)syp[bi], IMG_H - 2);
        const int base = y0 * IMG_W + x0;
        const float* img = imgb + (size_t)bi * img_stride;
#pragma unroll
        for (int ch = 0; ch < 3; ++ch) {
            const float* pc = img + ch * PLANE + base;
            v[bi][ch * 2 + 0] = *reinterpret_cast<const float2*>(pc);
            v[bi][ch * 2 + 1] = *reinterpret_cast<const float2*>(pc + IMG_W);
        }
    }

    // ---- phase C: blend all batches into registers
    float res[BCHUNK][3];
#pragma unroll
    for (int bi = 0; bi < BCHUNK; ++bi) {
        const float x = sxp[bi];
        const float y = syp[bi];
        const float wx = x - (float)min((int)x, IMG_W - 2);
        const float wy = y - (float)min((int)y, IMG_H - 2);
#pragma unroll
        for (int ch = 0; ch < 3; ++ch) {
            const float2 r0 = v[bi][ch * 2 + 0];
            const float2 r1 = v[bi][ch * 2 + 1];
            const float top = fmaf(wx, r0.y - r0.x, r0.x);
            const float bot = fmaf(wx, r1.y - r1.x, r1.x);
            res[bi][ch]     = fmaf(wy, bot - top, top);
        }
    }

    // ---- phase D: all stores at the end (nothing waits on them; NT keeps
    // 37 MB of write traffic out of the already-overflowing L2).
#pragma unroll
    for (int bi = 0; bi < BCHUNK; ++bi) {
        float* op = outb + (size_t)bi * img_stride;
#pragma unroll
        for (int ch = 0; ch < 3; ++ch)
            __builtin_nontemporal_store(res[bi][ch], op + ch * PLANE);
    }
}

extern "C" void kernel_launch(void* const* d_in, const int* in_sizes, int n_in,
                              void* d_out, int out_size, void* d_ws, size_t ws_size,
                              hipStream_t stream) {
    const float* cloth = (const float*)d_in[0];
    const float* theta = (const float*)d_in[1];
    float* out = (float*)d_out;

    tps_warp_kernel<<<dim3(NWG), dim3(256), 0, stream>>>(cloth, theta, out);
}

// Round 8
// 36.896 us; speedup vs baseline: 1.3533x; 1.0171x over previous
//
#include <hip/hip_runtime.h>

constexpr int GRID_SZ = 5;
constexpr int N_CTRL  = 25;
constexpr int IMG_H   = 256;
constexpr int IMG_W   = 192;
constexpr int BATCH   = 64;
constexpr int BCHUNK  = 4;    // batches per block; ALL prefetched (depth-4 MLP)
constexpr int PLANE   = IMG_H * IMG_W;
constexpr int PIX_BLOCKS = PLANE / 256;             // 192
constexpr int NWG = PIX_BLOCKS * (BATCH / BCHUNK);  // 3072, divisible by 8
constexpr float RBF_SCALE = 10.0f;
constexpr float OFF_SCALE = 0.3f;

__global__ __launch_bounds__(256) void tps_warp_kernel(
    const float* __restrict__ cloth,   // (64,3,256,192)
    const float* __restrict__ theta,   // (64,50)
    float* __restrict__ out)           // (64,3,256,192)
{
    // XCD-contiguous swizzle (keeps HBM FETCH at compulsory ~17 MB).
    const int flat = blockIdx.x;
    const int wg   = (flat & 7) * (NWG / 8) + (flat >> 3);
    const int pb   = wg % PIX_BLOCKS;
    const int bc   = wg / PIX_BLOCKS;
    const int b0   = bc * BCHUNK;

    const int pix = pb * 256 + threadIdx.x;
    const int hh = pix / IMG_W;
    const int ww = pix - hh * IMG_W;
    const float mx = -1.0f + (2.0f / (IMG_W - 1)) * (float)ww;
    const float my = -1.0f + (2.0f / (IMG_H - 1)) * (float)hh;

    // separable RBF basis: 10 exps + 25 muls; OFF_SCALE folded in.
    float ex[GRID_SZ], ey[GRID_SZ];
#pragma unroll
    for (int k = 0; k < GRID_SZ; ++k) {
        const float c = -0.9f + 0.45f * (float)k;
        const float dx = mx - c;
        const float dy = my - c;
        ex[k] = __expf(-dx * dx * RBF_SCALE);
        ey[k] = __expf(-dy * dy * RBF_SCALE);
    }
    float wgt[N_CTRL];
#pragma unroll
    for (int n = 0; n < N_CTRL; ++n)
        wgt[n] = OFF_SCALE * ex[n % GRID_SZ] * ey[n / GRID_SZ];

    // ---- phase A: sample coords per batch (theta via SGPR s_loads, no LDS)
    float sxp[BCHUNK], syp[BCHUNK];
#pragma unroll
    for (int bi = 0; bi < BCHUNK; ++bi) {
        const float* __restrict__ th = theta + (size_t)(b0 + bi) * (2 * N_CTRL);
        float ox = 0.0f, oy = 0.0f;
#pragma unroll
        for (int n = 0; n < N_CTRL; ++n) {
            ox = fmaf(th[2 * n + 0], wgt[n], ox);
            oy = fmaf(th[2 * n + 1], wgt[n], oy);
        }
        const float gx = fminf(fmaxf(mx + ox, -1.0f), 1.0f);
        const float gy = fminf(fmaxf(my + oy, -1.0f), 1.0f);
        sxp[bi] = (gx + 1.0f) * (0.5f * (float)(IMG_W - 1));  // in [0, W-1]
        syp[bi] = (gy + 1.0f) * (0.5f * (float)(IMG_H - 1));  // in [0, H-1]
    }

    const size_t img_stride = (size_t)3 * PLANE;
    const float* imgb = cloth + (size_t)b0 * img_stride;
    float*       outb = out   + (size_t)b0 * img_stride + pix;

    // ---- phase B: issue ALL 24 gather loads. R7 lesson: without a fence the
    // register-pressure-minimizing scheduler sinks each load to just before
    // its consume (VGPR_Count was 32 < the 48 floats of v[] alone), silently
    // re-serializing the "pipeline" into load->waitcnt(0)->blend chains.
    float2 v[BCHUNK][6];     // [batch][ch*2 + row] — all statically indexed
#pragma unroll
    for (int bi = 0; bi < BCHUNK; ++bi) {
        const int x0 = min((int)sxp[bi], IMG_W - 2);
        const int y0 = min((int)syp[bi], IMG_H - 2);
        const int base = y0 * IMG_W + x0;
        const float* img = imgb + (size_t)bi * img_stride;
#pragma unroll
        for (int ch = 0; ch < 3; ++ch) {
            const float* pc = img + ch * PLANE + base;
            v[bi][ch * 2 + 0] = *reinterpret_cast<const float2*>(pc);
            v[bi][ch * 2 + 1] = *reinterpret_cast<const float2*>(pc + IMG_W);
        }
    }

    // HARD scheduling fence: nothing moves across. Forces all 24 loads to be
    // issued (and their dest VGPRs live) before the first blend's s_waitcnt.
    __builtin_amdgcn_sched_barrier(0);

    // ---- phase C: blend all batches into registers
    float res[BCHUNK][3];
#pragma unroll
    for (int bi = 0; bi < BCHUNK; ++bi) {
        const float x = sxp[bi];
        const float y = syp[bi];
        const float wx = x - (float)min((int)x, IMG_W - 2);
        const float wy = y - (float)min((int)y, IMG_H - 2);
#pragma unroll
        for (int ch = 0; ch < 3; ++ch) {
            const float2 r0 = v[bi][ch * 2 + 0];
            const float2 r1 = v[bi][ch * 2 + 1];
            const float top = fmaf(wx, r0.y - r0.x, r0.x);
            const float bot = fmaf(wx, r1.y - r1.x, r1.x);
            res[bi][ch]     = fmaf(wy, bot - top, top);
        }
    }

    // ---- phase D: all stores at the end (nothing waits on them; NT keeps
    // 37 MB of write traffic out of the L2).
#pragma unroll
    for (int bi = 0; bi < BCHUNK; ++bi) {
        float* op = outb + (size_t)bi * img_stride;
#pragma unroll
        for (int ch = 0; ch < 3; ++ch)
            __builtin_nontemporal_store(res[bi][ch], op + ch * PLANE);
    }
}

extern "C" void kernel_launch(void* const* d_in, const int* in_sizes, int n_in,
                              void* d_out, int out_size, void* d_ws, size_t ws_size,
                              hipStream_t stream) {
    const float* cloth = (const float*)d_in[0];
    const float* theta = (const float*)d_in[1];
    float* out = (float*)d_out;

    tps_warp_kernel<<<dim3(NWG), dim3(256), 0, stream>>>(cloth, theta, out);
}